// Round 5
// baseline (398.372 us; speedup 1.0000x reference)
//
#include <hip/hip_runtime.h>

typedef unsigned short u16;
typedef __attribute__((ext_vector_type(8))) short short8;   // 8 x bf16 (4 VGPRs)
typedef __attribute__((ext_vector_type(4))) float f32x4;    // MFMA C/D frag

#define DEVI __device__ __forceinline__

DEVI float u2f(u16 u) {
    unsigned int x = ((unsigned int)u) << 16;
    float f; __builtin_memcpy(&f, &x, 4); return f;
}
DEVI u16 f2u(float f) {  // RNE bf16 (finite values)
    unsigned int x; __builtin_memcpy(&x, &f, 4);
    x = (x + 0x7fffu + ((x >> 16) & 1u)) >> 16;
    return (u16)x;
}
DEVI unsigned int fbits(float f) {
    unsigned int x; __builtin_memcpy(&x, &f, 4); return x;
}
DEVI float exp2_fast(float x) {
#if __has_builtin(__builtin_amdgcn_exp2f)
    return __builtin_amdgcn_exp2f(x);        // single v_exp_f32
#else
    return exp2f(x);
#endif
}
// async global->LDS, 16B per lane; lds base must be wave-uniform (m104/m108)
DEVI void gld16(const u16* g, u16* ldsbase) {
    __builtin_amdgcn_global_load_lds(
        (const __attribute__((address_space(1))) unsigned int*)g,
        (__attribute__((address_space(3))) unsigned int*)ldsbase, 16, 0, 0);
}

// ---------------------------------------------------------------------------
// Prep (one launch): blocks 0..4095 convert x fp32->bf16 (8 floats/thread);
// blocks 4096..6655 transpose the four weight matrices to K-inner bf16.
// grid 6656, block 256.
__global__ __launch_bounds__(256) void prep(
    const float* __restrict__ x,
    const float* __restrict__ Wq, const float* __restrict__ Wk,
    const float* __restrict__ Wv, const float* __restrict__ Wo,
    u16* __restrict__ xbf, u16* __restrict__ WTqkv, u16* __restrict__ WoT)
{
    __shared__ u16 T[64 * 72];
    int id = blockIdx.x;
    const int tid = threadIdx.x;
    if (id < 4096) {
        int g = (id * 256 + tid) * 8;
        float4 a = *(const float4*)&x[g];
        float4 c = *(const float4*)&x[g + 4];
        short8 v;
        v[0]=(short)f2u(a.x); v[1]=(short)f2u(a.y); v[2]=(short)f2u(a.z); v[3]=(short)f2u(a.w);
        v[4]=(short)f2u(c.x); v[5]=(short)f2u(c.y); v[6]=(short)f2u(c.z); v[7]=(short)f2u(c.w);
        *(short8*)&xbf[g] = v;
        return;
    }
    id -= 4096;
    const float* W; u16* WT; int N, bx, by;
    if (id < 1024)      {            W = Wo; WT = WoT;   N = 2048; bx = id & 31; by = id >> 5; }
    else if (id < 2048) { id -= 1024; W = Wq; WT = WTqkv; N = 2048; bx = id & 31; by = id >> 5; }
    else if (id < 2304) { id -= 2048; W = Wk; WT = WTqkv + (size_t)2048 * 2048; N = 512; bx = id & 7; by = id >> 3; }
    else                { id -= 2304; W = Wv; WT = WTqkv + (size_t)2560 * 2048; N = 512; bx = id & 7; by = id >> 3; }
    const int K = 2048;
    const int k0 = by * 64, n0 = bx * 64;
#pragma unroll
    for (int i = 0; i < 2; ++i) {
        int c = tid + i * 256;              // 0..511
        int row = c >> 3, n8 = (c & 7) * 8;
        const float* src = &W[(size_t)(k0 + row) * N + n0 + n8];
#pragma unroll
        for (int j = 0; j < 8; ++j)
            T[(n8 + j) * 72 + row] = f2u(src[j]);
    }
    __syncthreads();
#pragma unroll
    for (int i = 0; i < 2; ++i) {
        int c = tid + i * 256;
        int n = c >> 3, k8 = (c & 7) * 8;
        *(short8*)&WT[(size_t)(n0 + n) * K + k0 + k8] = *(const short8*)&T[n * 72 + k8];
    }
}

// ---------------------------------------------------------------------------
// GEMM: C[M][N] = A[M][K] @ WT[N][K]^T (+ optional fp32 residual).
// m97 structure: unpadded [128][32] LDS tiles, global_load_lds width=16.
// If fuse_norm: N-tiles with n0<2560 get per-head RMSNorm fused in epilogue.
// C written fp32 if c_f32 else bf16.  grid (N/128, M/128), block 256.
__global__ __launch_bounds__(256) void gemm_lds(
    const u16* __restrict__ A, int lda,
    const u16* __restrict__ WT,
    void* __restrict__ C, int ldc, const float* __restrict__ resid, int c_f32,
    int M, int N, int K,
    const float* __restrict__ qg, const float* __restrict__ kg, int fuse_norm)
{
    __shared__ u16 As[128 * 32];
    __shared__ u16 Bs[128 * 32];
    const int tid = threadIdx.x;
    const int lane = tid & 63, w = tid >> 6;
    const int wm = w >> 1, wn = w & 1;
    const int l15 = lane & 15, quad = lane >> 4;
    const int r4 = lane >> 2, c4 = (lane & 3) * 8;  // DMA: lane->row/col-8
    const int m0 = blockIdx.y * 128, n0 = blockIdx.x * 128;

    f32x4 acc[4][4] = {};
    for (int k0 = 0; k0 < K; k0 += 32) {
#pragma unroll
        for (int j = 0; j < 2; ++j) {
            int row = w * 32 + j * 16;
            gld16(&WT[(size_t)(n0 + row + r4) * K + k0 + c4], &Bs[row * 32]);
            gld16(&A [(size_t)(m0 + row + r4) * lda + k0 + c4], &As[row * 32]);
        }
        __syncthreads();
        short8 a[4], b[4];
#pragma unroll
        for (int mt = 0; mt < 4; ++mt)
            a[mt] = *(const short8*)&As[(wm * 64 + mt * 16 + l15) * 32 + quad * 8];
#pragma unroll
        for (int nt = 0; nt < 4; ++nt)
            b[nt] = *(const short8*)&Bs[(wn * 64 + nt * 16 + l15) * 32 + quad * 8];
#pragma unroll
        for (int mt = 0; mt < 4; ++mt)
#pragma unroll
            for (int nt = 0; nt < 4; ++nt)
                acc[mt][nt] = __builtin_amdgcn_mfma_f32_16x16x32_bf16(a[mt], b[nt], acc[mt][nt], 0, 0, 0);
        __syncthreads();
    }

    if (fuse_norm && n0 < 2560) {
        const float* gamma = (n0 < 2048) ? qg : kg;
        float* red = (float*)As;             // 256 floats, As is dead
#pragma unroll
        for (int mt = 0; mt < 4; ++mt)
#pragma unroll
            for (int r = 0; r < 4; ++r) {
                float p = 0.f;
#pragma unroll
                for (int nt = 0; nt < 4; ++nt) p += acc[mt][nt][r] * acc[mt][nt][r];
#pragma unroll
                for (int msk = 1; msk < 16; msk <<= 1) p += __shfl_xor(p, msk);
                if (l15 == 0)
                    red[(wm * 64 + mt * 16 + quad * 4 + r) * 2 + wn] = p;
            }
        __syncthreads();
        float gv[4];
#pragma unroll
        for (int nt = 0; nt < 4; ++nt) gv[nt] = gamma[wn * 64 + nt * 16 + l15];
#pragma unroll
        for (int mt = 0; mt < 4; ++mt)
#pragma unroll
            for (int r = 0; r < 4; ++r) {
                int rl = wm * 64 + mt * 16 + quad * 4 + r;
                float m2 = red[rl * 2] + red[rl * 2 + 1];
                float sc = rsqrtf(m2 * (1.0f / 128.0f) + 1e-8f);
#pragma unroll
                for (int nt = 0; nt < 4; ++nt) acc[mt][nt][r] *= sc * gv[nt];
            }
    }

#pragma unroll
    for (int mt = 0; mt < 4; ++mt) {
#pragma unroll
        for (int r = 0; r < 4; ++r) {
            int row = m0 + wm * 64 + mt * 16 + quad * 4 + r;
#pragma unroll
            for (int nt = 0; nt < 4; ++nt) {
                int col = n0 + wn * 64 + nt * 16 + l15;
                float v = acc[mt][nt][r];
                if (resid) v += resid[(size_t)row * ldc + col];
                if (c_f32) ((float*)C)[(size_t)row * ldc + col] = v;
                else       ((u16*)C)[(size_t)row * ldc + col] = f2u(v);
            }
        }
    }
}

// ---------------------------------------------------------------------------
// V transpose: vT[(b*4+kvh)*128 + d][s] = qkv[(b*2048+s)][2560 + kvh*128 + d]
// grid (32, 4, 2), block 256.  (bf16)
__global__ __launch_bounds__(256) void vtrans(
    const u16* __restrict__ qkv, u16* __restrict__ vT)
{
    __shared__ u16 T[128 * 72];
    const int tid = threadIdx.x;
    const int t0 = blockIdx.x * 64;
    const int kvh = blockIdx.y, b = blockIdx.z;
#pragma unroll
    for (int i = 0; i < 4; ++i) {
        int c = tid + i * 256;                // 0..1023
        int tl = c >> 4, d8 = (c & 15) * 8;
        short8 v = *(const short8*)&qkv[(size_t)(b * 2048 + t0 + tl) * 3072 + 2560 + kvh * 128 + d8];
#pragma unroll
        for (int j = 0; j < 8; ++j)
            T[(d8 + j) * 72 + tl] = (u16)v[j];
    }
    __syncthreads();
#pragma unroll
    for (int i = 0; i < 4; ++i) {
        int c = tid + i * 256;
        int d = c >> 3, t8 = (c & 7) * 8;
        *(short8*)&vT[((size_t)(b * 4 + kvh) * 128 + d) * 2048 + t0 + t8] =
            *(const short8*)&T[d * 72 + t8];
    }
}

// ---------------------------------------------------------------------------
// Flash attention, causal, GQA, paired q-tiles (qt, 31-qt) => uniform 33
// kv-tiles/block.  S computed TRANSPOSED (mfma(K,Q) => kv=row, q=col) so the
// P matrix never touches LDS; PV A-frags built in-register via v_perm packs
// + lane shuffles.  Structure identical to the verified 354us baseline
// (single-buffer, 2 barriers/kv-iter, 35.8KB LDS — round-4 dbuf at 71.7KB
// halved residency and regressed; round-3 unbalanced grid regressed).
// NEW (VALU diet, softmax only):
//  - scale folded into exp2 domain: p = exp2(s*c1 - m*c1), c1=scale*log2e
//    (kills the 16 s*=scale muls/iter; exp is 1 fma + 1 v_exp)
//  - defer-max (T13, THR_RAW=64 => P <= 2^8.2~287, bf16/f32-safe): skip the
//    32-mul O-rescale + 4 broadcasts + alpha exp when __all(mx <= m_+64)
//  - tree-form max/sum reductions (shorter serial chains, max3-fusible)
// grid (16, 16, 2), block 256.
#define QS 136
#define VS 72
__global__ __launch_bounds__(256) void attn(
    u16* __restrict__ qkv, const u16* __restrict__ vT)
{
    __shared__ u16 lds[17920];               // 35,840 B
    u16* const Ks = lds;                     // [64][QS]   8704
    u16* const Vs = lds + 8704;              // [128][VS]  9216
    // Q staging reuses the whole region: Qsb[t] = lds + t*8704

    const int tid = threadIdx.x, lane = tid & 63, w = tid >> 6;
    const int l15 = lane & 15, quad = lane >> 4;
    const int h = blockIdx.y, b = blockIdx.z;
    const int kvh = h >> 2;
    const int qts[2] = { (int)blockIdx.x, 31 - (int)blockIdx.x };
    const float c1 = 0.08838834764831845f * 1.4426950408889634f; // scale*log2e

    // stage both Q tiles, pull fragments to registers
#pragma unroll
    for (int t = 0; t < 2; ++t)
#pragma unroll
        for (int i = 0; i < 4; ++i) {
            int c = tid + i * 256;
            int r = c >> 4, d8 = (c & 15) * 8;
            *(short8*)&lds[t * 8704 + r * QS + d8] =
                *(const short8*)&qkv[(size_t)(b * 2048 + qts[t] * 64 + r) * 3072 + h * 128 + d8];
        }
    __syncthreads();
    short8 qf[2][4];
#pragma unroll
    for (int t = 0; t < 2; ++t)
#pragma unroll
        for (int ks = 0; ks < 4; ++ks)
            qf[t][ks] = *(const short8*)&lds[t * 8704 + (w * 16 + l15) * QS + ks * 32 + quad * 8];
    __syncthreads();   // region about to be reused as Ks/Vs

    f32x4 o[2][8] = {};
    float m_[2] = { -1e30f, -1e30f }, l_[2] = { 0.f, 0.f };

    for (int kt = 0; kt <= qts[1]; ++kt) {
        const int kv0 = kt * 64;
#pragma unroll
        for (int i = 0; i < 4; ++i) {
            int c = tid + i * 256;
            int r = c >> 4, d8 = (c & 15) * 8;
            *(short8*)&Ks[r * QS + d8] =
                *(const short8*)&qkv[(size_t)(b * 2048 + kv0 + r) * 3072 + 2048 + kvh * 128 + d8];
        }
#pragma unroll
        for (int i = 0; i < 4; ++i) {
            int c = tid + i * 256;
            int d = c >> 3, t8 = (c & 7) * 8;
            *(short8*)&Vs[d * VS + t8] =
                *(const short8*)&vT[((size_t)(b * 4 + kvh) * 128 + d) * 2048 + kv0 + t8];
        }
        __syncthreads();

#pragma unroll
        for (int t = 0; t < 2; ++t) {
            if (kt > qts[t]) continue;       // tile done (block-uniform branch)
            // S^T = K Q^T : rows = kv (quad*4+r within 16-tile), cols = q (l15)
            f32x4 s[4];
#pragma unroll
            for (int nt = 0; nt < 4; ++nt) {
                f32x4 a = {};
#pragma unroll
                for (int ks = 0; ks < 4; ++ks) {
                    short8 kf = *(const short8*)&Ks[(nt * 16 + l15) * QS + ks * 32 + quad * 8];
                    a = __builtin_amdgcn_mfma_f32_16x16x32_bf16(kf, qf[t][ks], a, 0, 0, 0);
                }
                s[nt] = a;
            }
            // causal mask, RAW domain (diag tile only); local: kv vs q=w*16+l15
            if (kt == qts[t]) {
                int qrow = w * 16 + l15;
#pragma unroll
                for (int nt = 0; nt < 4; ++nt)
#pragma unroll
                    for (int r = 0; r < 4; ++r)
                        if (nt * 16 + quad * 4 + r > qrow) s[nt][r] = -1e30f;
            }
            // row max (raw), tree reduce + 2 cross-quad shuffles
            float x0 = fmaxf(fmaxf(s[0][0], s[0][1]), fmaxf(s[0][2], s[0][3]));
            float x1 = fmaxf(fmaxf(s[1][0], s[1][1]), fmaxf(s[1][2], s[1][3]));
            float x2 = fmaxf(fmaxf(s[2][0], s[2][1]), fmaxf(s[2][2], s[2][3]));
            float x3 = fmaxf(fmaxf(s[3][0], s[3][1]), fmaxf(s[3][2], s[3][3]));
            float mx = fmaxf(fmaxf(x0, x1), fmaxf(x2, x3));
            mx = fmaxf(mx, __shfl_xor(mx, 16));
            mx = fmaxf(mx, __shfl_xor(mx, 32));
            // defer-max: skip rescale while growth bounded (P <= 2^(64*c1))
            if (!__all(mx <= m_[t] + 64.0f)) {
                float mn = fmaxf(m_[t], mx);
                float alpha = exp2_fast((m_[t] - mn) * c1);
                m_[t] = mn;
                l_[t] *= alpha;
#pragma unroll
                for (int r = 0; r < 4; ++r) {
                    float ao = __shfl(alpha, quad * 4 + r);
#pragma unroll
                    for (int nto = 0; nto < 8; ++nto) o[t][nto][r] *= ao;
                }
            }
            // p = exp2(s*c1 - m*c1) : 1 fma + 1 v_exp per element
            float mnc = m_[t] * c1;
            float sum4[4];
#pragma unroll
            for (int nt = 0; nt < 4; ++nt) {
                float p0 = exp2_fast(s[nt][0] * c1 - mnc);
                float p1 = exp2_fast(s[nt][1] * c1 - mnc);
                float p2 = exp2_fast(s[nt][2] * c1 - mnc);
                float p3 = exp2_fast(s[nt][3] * c1 - mnc);
                s[nt][0] = p0; s[nt][1] = p1; s[nt][2] = p2; s[nt][3] = p3;
                sum4[nt] = (p0 + p1) + (p2 + p3);
            }
            float sum = (sum4[0] + sum4[1]) + (sum4[2] + sum4[3]);
            sum += __shfl_xor(sum, 16);
            sum += __shfl_xor(sum, 32);
            l_[t] += sum;
            // pack P pairs to bf16 (truncate): pk[nt][i] = [p[2i] | p[2i+1]<<16]
            unsigned int pk[4][2];
#pragma unroll
            for (int nt = 0; nt < 4; ++nt)
#pragma unroll
                for (int i = 0; i < 2; ++i)
                    pk[nt][i] = __builtin_amdgcn_perm(
                        fbits(s[nt][2 * i + 1]), fbits(s[nt][2 * i]), 0x07060302u);
            // build PV A-frags: lane(l15,quad) chunk c needs kv = 32c+quad*8+j
            int af[2][4];
#pragma unroll
            for (int c = 0; c < 2; ++c)
#pragma unroll
                for (int d = 0; d < 4; ++d) {
                    int src = l15 + 16 * ((quad & 1) * 2 + (d >> 1));
                    int v0 = __shfl((int)pk[2 * c][d & 1], src);
                    int v1 = __shfl((int)pk[2 * c + 1][d & 1], src);
                    af[c][d] = (quad >= 2) ? v1 : v0;
                }
            union { int i4[4]; short8 s8; } ua0, ua1;
#pragma unroll
            for (int d = 0; d < 4; ++d) { ua0.i4[d] = af[0][d]; ua1.i4[d] = af[1][d]; }
            // O += P V
#pragma unroll
            for (int nto = 0; nto < 8; ++nto) {
                short8 bv0 = *(const short8*)&Vs[(nto * 16 + l15) * VS + quad * 8];
                short8 bv1 = *(const short8*)&Vs[(nto * 16 + l15) * VS + 32 + quad * 8];
                o[t][nto] = __builtin_amdgcn_mfma_f32_16x16x32_bf16(ua0.s8, bv0, o[t][nto], 0, 0, 0);
                o[t][nto] = __builtin_amdgcn_mfma_f32_16x16x32_bf16(ua1.s8, bv1, o[t][nto], 0, 0, 0);
            }
        }
        __syncthreads();   // before restaging Ks/Vs
    }
    // write O in-place over the Q slice (row stride 3072)
#pragma unroll
    for (int t = 0; t < 2; ++t) {
        float rl = 1.0f / l_[t];
#pragma unroll
        for (int r = 0; r < 4; ++r) {
            float inv = __shfl(rl, quad * 4 + r);
            int row = qts[t] * 64 + w * 16 + quad * 4 + r;
#pragma unroll
            for (int nto = 0; nto < 8; ++nto)
                qkv[(size_t)(b * 2048 + row) * 3072 + h * 128 + nto * 16 + l15] =
                    f2u(o[t][nto][r] * inv);
        }
    }
}

// ---------------------------------------------------------------------------
// Workspace layout (peak 46.1 MiB, proven):
//   [0,         8388608)  WoT   [2048][2048]   live until final GEMM
//   [8388608,  33554432)  QKV   [4096][3072]   q-slice becomes O in-place
//   [33554432, 37748736)  vT    [8][128][2048] written AFTER WTqkv is dead
//   [33554432, 46137344)  WTqkv [3072][2048]   dead after QKV GEMM
// xbf (bf16 copy of x, 16.8 MB) lives in d_out (dead until final GEMM).
extern "C" void kernel_launch(void* const* d_in, const int* in_sizes, int n_in,
                              void* d_out, int out_size, void* d_ws, size_t ws_size,
                              hipStream_t stream) {
    const float* x  = (const float*)d_in[0];   // [2,2048,2048] fp32
    const float* Wq = (const float*)d_in[1];   // [2048,2048]
    const float* Wk = (const float*)d_in[2];   // [2048,512]
    const float* Wv = (const float*)d_in[3];   // [2048,512]
    const float* Wo = (const float*)d_in[4];   // [2048,2048]
    const float* qg = (const float*)d_in[5];   // [128]
    const float* kg = (const float*)d_in[6];   // [128]

    char* ws = (char*)d_ws;
    u16* WoT   = (u16*)(ws);
    u16* QKV   = (u16*)(ws + 8388608);
    u16* vT    = (u16*)(ws + 33554432);
    u16* WTqkv = (u16*)(ws + 33554432);
    u16* xbf   = (u16*)d_out;                  // 16.8 MB of 33.5 MB; dead at GEMM2

    // 0. x->bf16 + all weight transposes, one launch
    prep<<<dim3(6656), 256, 0, stream>>>(x, Wq, Wk, Wv, Wo, xbf, WTqkv, WoT);

    // 1. QKV projection with fused per-head RMSNorm on q/k tiles
    gemm_lds<<<dim3(24, 32), 256, 0, stream>>>(xbf, 2048, WTqkv, QKV, 3072,
                                               nullptr, 0, 4096, 3072, 2048,
                                               qg, kg, 1);

    // 2. V transpose (WTqkv now dead; vT overlays it)
    vtrans<<<dim3(32, 4, 2), 256, 0, stream>>>(QKV, vT);

    // 3. causal GQA flash attention (paired q-tiles, register-resident P,
    //    exp2-domain softmax + defer-max)
    attn<<<dim3(16, 16, 2), 256, 0, stream>>>(QKV, vT);

    // 4. output projection + residual (C = d_out fp32)
    gemm_lds<<<dim3(16, 32), 256, 0, stream>>>(QKV, 3072, WoT, d_out, 2048,
                                               x, 1, 4096, 2048, 2048,
                                               nullptr, nullptr, 0);
}

// Round 6
// 370.610 us; speedup vs baseline: 1.0749x; 1.0749x over previous
//
#include <hip/hip_runtime.h>

typedef unsigned short u16;
typedef __attribute__((ext_vector_type(8))) short short8;   // 8 x bf16 (4 VGPRs)
typedef __attribute__((ext_vector_type(4))) float f32x4;    // MFMA C/D frag

#define DEVI __device__ __forceinline__

DEVI float u2f(u16 u) {
    unsigned int x = ((unsigned int)u) << 16;
    float f; __builtin_memcpy(&f, &x, 4); return f;
}
DEVI u16 f2u(float f) {  // RNE bf16 (finite values)
    unsigned int x; __builtin_memcpy(&x, &f, 4);
    x = (x + 0x7fffu + ((x >> 16) & 1u)) >> 16;
    return (u16)x;
}
DEVI unsigned int fbits(float f) {
    unsigned int x; __builtin_memcpy(&x, &f, 4); return x;
}
// async global->LDS, 16B per lane; lds base must be wave-uniform (m104/m108)
DEVI void gld16(const u16* g, u16* ldsbase) {
    __builtin_amdgcn_global_load_lds(
        (const __attribute__((address_space(1))) unsigned int*)g,
        (__attribute__((address_space(3))) unsigned int*)ldsbase, 16, 0, 0);
}

// ---------------------------------------------------------------------------
// Prep (one launch): blocks 0..4095 convert x fp32->bf16 (8 floats/thread);
// blocks 4096..6655 transpose the four weight matrices to K-inner bf16.
// grid 6656, block 256.
__global__ __launch_bounds__(256) void prep(
    const float* __restrict__ x,
    const float* __restrict__ Wq, const float* __restrict__ Wk,
    const float* __restrict__ Wv, const float* __restrict__ Wo,
    u16* __restrict__ xbf, u16* __restrict__ WTqkv, u16* __restrict__ WoT)
{
    __shared__ u16 T[64 * 72];
    int id = blockIdx.x;
    const int tid = threadIdx.x;
    if (id < 4096) {
        int g = (id * 256 + tid) * 8;
        float4 a = *(const float4*)&x[g];
        float4 c = *(const float4*)&x[g + 4];
        short8 v;
        v[0]=(short)f2u(a.x); v[1]=(short)f2u(a.y); v[2]=(short)f2u(a.z); v[3]=(short)f2u(a.w);
        v[4]=(short)f2u(c.x); v[5]=(short)f2u(c.y); v[6]=(short)f2u(c.z); v[7]=(short)f2u(c.w);
        *(short8*)&xbf[g] = v;
        return;
    }
    id -= 4096;
    const float* W; u16* WT; int N, bx, by;
    if (id < 1024)      {            W = Wo; WT = WoT;   N = 2048; bx = id & 31; by = id >> 5; }
    else if (id < 2048) { id -= 1024; W = Wq; WT = WTqkv; N = 2048; bx = id & 31; by = id >> 5; }
    else if (id < 2304) { id -= 2048; W = Wk; WT = WTqkv + (size_t)2048 * 2048; N = 512; bx = id & 7; by = id >> 3; }
    else                { id -= 2304; W = Wv; WT = WTqkv + (size_t)2560 * 2048; N = 512; bx = id & 7; by = id >> 3; }
    const int K = 2048;
    const int k0 = by * 64, n0 = bx * 64;
#pragma unroll
    for (int i = 0; i < 2; ++i) {
        int c = tid + i * 256;              // 0..511
        int row = c >> 3, n8 = (c & 7) * 8;
        const float* src = &W[(size_t)(k0 + row) * N + n0 + n8];
#pragma unroll
        for (int j = 0; j < 8; ++j)
            T[(n8 + j) * 72 + row] = f2u(src[j]);
    }
    __syncthreads();
#pragma unroll
    for (int i = 0; i < 2; ++i) {
        int c = tid + i * 256;
        int n = c >> 3, k8 = (c & 7) * 8;
        *(short8*)&WT[(size_t)(n0 + n) * K + k0 + k8] = *(const short8*)&T[n * 72 + k8];
    }
}

// ---------------------------------------------------------------------------
// GEMM: C[M][N] = A[M][K] @ WT[N][K]^T (+ optional fp32 residual).
// m97 structure: unpadded [128][32] LDS tiles, global_load_lds width=16.
// If fuse_norm: N-tiles with n0<2560 get per-head RMSNorm fused in epilogue.
// C written fp32 if c_f32 else bf16.  grid (N/128, M/128), block 256.
__global__ __launch_bounds__(256) void gemm_lds(
    const u16* __restrict__ A, int lda,
    const u16* __restrict__ WT,
    void* __restrict__ C, int ldc, const float* __restrict__ resid, int c_f32,
    int M, int N, int K,
    const float* __restrict__ qg, const float* __restrict__ kg, int fuse_norm)
{
    __shared__ u16 As[128 * 32];
    __shared__ u16 Bs[128 * 32];
    const int tid = threadIdx.x;
    const int lane = tid & 63, w = tid >> 6;
    const int wm = w >> 1, wn = w & 1;
    const int l15 = lane & 15, quad = lane >> 4;
    const int r4 = lane >> 2, c4 = (lane & 3) * 8;  // DMA: lane->row/col-8
    const int m0 = blockIdx.y * 128, n0 = blockIdx.x * 128;

    f32x4 acc[4][4] = {};
    for (int k0 = 0; k0 < K; k0 += 32) {
#pragma unroll
        for (int j = 0; j < 2; ++j) {
            int row = w * 32 + j * 16;
            gld16(&WT[(size_t)(n0 + row + r4) * K + k0 + c4], &Bs[row * 32]);
            gld16(&A [(size_t)(m0 + row + r4) * lda + k0 + c4], &As[row * 32]);
        }
        __syncthreads();
        short8 a[4], b[4];
#pragma unroll
        for (int mt = 0; mt < 4; ++mt)
            a[mt] = *(const short8*)&As[(wm * 64 + mt * 16 + l15) * 32 + quad * 8];
#pragma unroll
        for (int nt = 0; nt < 4; ++nt)
            b[nt] = *(const short8*)&Bs[(wn * 64 + nt * 16 + l15) * 32 + quad * 8];
#pragma unroll
        for (int mt = 0; mt < 4; ++mt)
#pragma unroll
            for (int nt = 0; nt < 4; ++nt)
                acc[mt][nt] = __builtin_amdgcn_mfma_f32_16x16x32_bf16(a[mt], b[nt], acc[mt][nt], 0, 0, 0);
        __syncthreads();
    }

    if (fuse_norm && n0 < 2560) {
        const float* gamma = (n0 < 2048) ? qg : kg;
        float* red = (float*)As;             // 256 floats, As is dead
#pragma unroll
        for (int mt = 0; mt < 4; ++mt)
#pragma unroll
            for (int r = 0; r < 4; ++r) {
                float p = 0.f;
#pragma unroll
                for (int nt = 0; nt < 4; ++nt) p += acc[mt][nt][r] * acc[mt][nt][r];
#pragma unroll
                for (int msk = 1; msk < 16; msk <<= 1) p += __shfl_xor(p, msk);
                if (l15 == 0)
                    red[(wm * 64 + mt * 16 + quad * 4 + r) * 2 + wn] = p;
            }
        __syncthreads();
        float gv[4];
#pragma unroll
        for (int nt = 0; nt < 4; ++nt) gv[nt] = gamma[wn * 64 + nt * 16 + l15];
#pragma unroll
        for (int mt = 0; mt < 4; ++mt)
#pragma unroll
            for (int r = 0; r < 4; ++r) {
                int rl = wm * 64 + mt * 16 + quad * 4 + r;
                float m2 = red[rl * 2] + red[rl * 2 + 1];
                float sc = rsqrtf(m2 * (1.0f / 128.0f) + 1e-8f);
#pragma unroll
                for (int nt = 0; nt < 4; ++nt) acc[mt][nt][r] *= sc * gv[nt];
            }
    }

#pragma unroll
    for (int mt = 0; mt < 4; ++mt) {
#pragma unroll
        for (int r = 0; r < 4; ++r) {
            int row = m0 + wm * 64 + mt * 16 + quad * 4 + r;
#pragma unroll
            for (int nt = 0; nt < 4; ++nt) {
                int col = n0 + wn * 64 + nt * 16 + l15;
                float v = acc[mt][nt][r];
                if (resid) v += resid[(size_t)row * ldc + col];
                if (c_f32) ((float*)C)[(size_t)row * ldc + col] = v;
                else       ((u16*)C)[(size_t)row * ldc + col] = f2u(v);
            }
        }
    }
}

// ---------------------------------------------------------------------------
// V transpose: vT[(b*4+kvh)*128 + d][s] = qkv[(b*2048+s)][2560 + kvh*128 + d]
// grid (32, 4, 2), block 256.  (bf16)
__global__ __launch_bounds__(256) void vtrans(
    const u16* __restrict__ qkv, u16* __restrict__ vT)
{
    __shared__ u16 T[128 * 72];
    const int tid = threadIdx.x;
    const int t0 = blockIdx.x * 64;
    const int kvh = blockIdx.y, b = blockIdx.z;
#pragma unroll
    for (int i = 0; i < 4; ++i) {
        int c = tid + i * 256;                // 0..1023
        int tl = c >> 4, d8 = (c & 15) * 8;
        short8 v = *(const short8*)&qkv[(size_t)(b * 2048 + t0 + tl) * 3072 + 2560 + kvh * 128 + d8];
#pragma unroll
        for (int j = 0; j < 8; ++j)
            T[(d8 + j) * 72 + tl] = (u16)v[j];
    }
    __syncthreads();
#pragma unroll
    for (int i = 0; i < 4; ++i) {
        int c = tid + i * 256;
        int d = c >> 3, t8 = (c & 7) * 8;
        *(short8*)&vT[((size_t)(b * 4 + kvh) * 128 + d) * 2048 + t0 + t8] =
            *(const short8*)&T[d * 72 + t8];
    }
}

// ---------------------------------------------------------------------------
// Flash attention, causal, GQA, paired q-tiles (qt, 31-qt).  S computed
// TRANSPOSED (mfma(K,Q) => kv=row, q=col) so the P matrix never touches LDS:
// softmax state is one scalar/lane (q=l15), reduction = 15 in-lane ops + 2
// cross-quad shuffles, PV A-frags built in-register via v_perm + shuffles.
// 512 threads / 8 waves per block.  Waves 0-3 own tile qts[0], waves 4-7
// own tile qts[1] — the two tile-computations per kv-iter run in PARALLEL
// wave-groups instead of sequentially.  Same grid, 2x resident waves/CU
// (16 vs 8), and ~halved per-wave VGPR state (o[8] not o[2][8], qf[4] not
// qf[2][4]) — keeps VGPR_Count under the measured 128 occupancy cliff
// (r4: 136 VGPR and r5: 144 VGPR both halved residency to 1 block/CU).
// 2 barriers/kv-iter unchanged, LDS 35.8 KB unchanged.
// grid (16, 16, 2), block 512.
#define QS 136
#define VS 72
__global__ __launch_bounds__(512) void attn(
    u16* __restrict__ qkv, const u16* __restrict__ vT)
{
    __shared__ u16 lds[17920];               // 35,840 B
    u16* const Ks = lds;                     // [64][QS]   8704
    u16* const Vs = lds + 8704;              // [128][VS]  9216
    // Q staging reuses the whole region: Qsb[t] = lds + t*8704

    const int tid = threadIdx.x, lane = tid & 63, w = tid >> 6;
    const int t = w >> 2, wq = w & 3;        // tile owner, q-slice in tile
    const int l15 = lane & 15, quad = lane >> 4;
    const int h = blockIdx.y, b = blockIdx.z;
    const int kvh = h >> 2;
    const int qts[2] = { (int)blockIdx.x, 31 - (int)blockIdx.x };
    const int qt = qts[t];                   // this wave's q-tile
    const float scale = 0.08838834764831845f;

    // stage both Q tiles, pull fragments to registers
#pragma unroll
    for (int ts = 0; ts < 2; ++ts)
#pragma unroll
        for (int i = 0; i < 2; ++i) {
            int c = tid + i * 512;
            int r = c >> 4, d8 = (c & 15) * 8;
            *(short8*)&lds[ts * 8704 + r * QS + d8] =
                *(const short8*)&qkv[(size_t)(b * 2048 + qts[ts] * 64 + r) * 3072 + h * 128 + d8];
        }
    __syncthreads();
    short8 qf[4];
#pragma unroll
    for (int ks = 0; ks < 4; ++ks)
        qf[ks] = *(const short8*)&lds[t * 8704 + (wq * 16 + l15) * QS + ks * 32 + quad * 8];
    __syncthreads();   // region about to be reused as Ks/Vs

    f32x4 o[8] = {};
    float m_ = -1e30f, l_ = 0.f;

    for (int kt = 0; kt <= qts[1]; ++kt) {
        const int kv0 = kt * 64;
#pragma unroll
        for (int i = 0; i < 2; ++i) {
            int c = tid + i * 512;
            int r = c >> 4, d8 = (c & 15) * 8;
            *(short8*)&Ks[r * QS + d8] =
                *(const short8*)&qkv[(size_t)(b * 2048 + kv0 + r) * 3072 + 2048 + kvh * 128 + d8];
        }
#pragma unroll
        for (int i = 0; i < 2; ++i) {
            int c = tid + i * 512;
            int d = c >> 3, t8 = (c & 7) * 8;
            *(short8*)&Vs[d * VS + t8] =
                *(const short8*)&vT[((size_t)(b * 4 + kvh) * 128 + d) * 2048 + kv0 + t8];
        }
        __syncthreads();

        if (kt <= qt) {                      // wave-uniform: this tile active
            // S^T = K Q^T : rows = kv (quad*4+r within 16-tile), cols = q (l15)
            f32x4 s[4];
#pragma unroll
            for (int nt = 0; nt < 4; ++nt) {
                f32x4 a = {};
#pragma unroll
                for (int ks = 0; ks < 4; ++ks) {
                    short8 kf = *(const short8*)&Ks[(nt * 16 + l15) * QS + ks * 32 + quad * 8];
                    a = __builtin_amdgcn_mfma_f32_16x16x32_bf16(kf, qf[ks], a, 0, 0, 0);
                }
                s[nt] = a;
            }
            // scale + causal mask (diag tile only); local: kv vs q = wq*16+l15
            if (kt == qt) {
                int qrow = wq * 16 + l15;
#pragma unroll
                for (int nt = 0; nt < 4; ++nt)
#pragma unroll
                    for (int r = 0; r < 4; ++r) {
                        float v = s[nt][r] * scale;
                        if (nt * 16 + quad * 4 + r > qrow) v = -1e30f;
                        s[nt][r] = v;
                    }
            } else {
#pragma unroll
                for (int nt = 0; nt < 4; ++nt)
#pragma unroll
                    for (int r = 0; r < 4; ++r) s[nt][r] *= scale;
            }
            // online softmax, one q-row per lane (q = l15)
            float mx = s[0][0];
#pragma unroll
            for (int nt = 0; nt < 4; ++nt)
#pragma unroll
                for (int r = 0; r < 4; ++r) mx = fmaxf(mx, s[nt][r]);
            mx = fmaxf(mx, __shfl_xor(mx, 16));
            mx = fmaxf(mx, __shfl_xor(mx, 32));
            float mn = fmaxf(m_, mx);
            float alpha = __expf(m_ - mn);
            m_ = mn;
            float sum = 0.f;
#pragma unroll
            for (int nt = 0; nt < 4; ++nt)
#pragma unroll
                for (int r = 0; r < 4; ++r) {
                    float p = __expf(s[nt][r] - mn);
                    s[nt][r] = p;
                    sum += p;
                }
            sum += __shfl_xor(sum, 16);
            sum += __shfl_xor(sum, 32);
            l_ = l_ * alpha + sum;
            // pack P pairs to bf16 (truncate): pk[nt][i] = [p[2i] | p[2i+1]<<16]
            unsigned int pk[4][2];
#pragma unroll
            for (int nt = 0; nt < 4; ++nt)
#pragma unroll
                for (int i = 0; i < 2; ++i)
                    pk[nt][i] = __builtin_amdgcn_perm(
                        fbits(s[nt][2 * i + 1]), fbits(s[nt][2 * i]), 0x07060302u);
            // build PV A-frags: lane(l15,quad) chunk c needs kv = 32c+quad*8+j
            int af[2][4];
#pragma unroll
            for (int c = 0; c < 2; ++c)
#pragma unroll
                for (int d = 0; d < 4; ++d) {
                    int src = l15 + 16 * ((quad & 1) * 2 + (d >> 1));
                    int v0 = __shfl((int)pk[2 * c][d & 1], src);
                    int v1 = __shfl((int)pk[2 * c + 1][d & 1], src);
                    af[c][d] = (quad >= 2) ? v1 : v0;
                }
            union { int i4[4]; short8 s8; } ua0, ua1;
#pragma unroll
            for (int d = 0; d < 4; ++d) { ua0.i4[d] = af[0][d]; ua1.i4[d] = af[1][d]; }
            // rescale O rows (q = quad*4+r) by alpha broadcast from lane q
#pragma unroll
            for (int r = 0; r < 4; ++r) {
                float ao = __shfl(alpha, quad * 4 + r);
#pragma unroll
                for (int nto = 0; nto < 8; ++nto) o[nto][r] *= ao;
            }
            // O += P V
#pragma unroll
            for (int nto = 0; nto < 8; ++nto) {
                short8 bv0 = *(const short8*)&Vs[(nto * 16 + l15) * VS + quad * 8];
                short8 bv1 = *(const short8*)&Vs[(nto * 16 + l15) * VS + 32 + quad * 8];
                o[nto] = __builtin_amdgcn_mfma_f32_16x16x32_bf16(ua0.s8, bv0, o[nto], 0, 0, 0);
                o[nto] = __builtin_amdgcn_mfma_f32_16x16x32_bf16(ua1.s8, bv1, o[nto], 0, 0, 0);
            }
        }
        __syncthreads();   // before restaging Ks/Vs
    }
    // write O in-place over the Q slice (row stride 3072)
    {
        float rl = 1.0f / l_;
#pragma unroll
        for (int r = 0; r < 4; ++r) {
            float inv = __shfl(rl, quad * 4 + r);
            int row = qt * 64 + wq * 16 + quad * 4 + r;
#pragma unroll
            for (int nto = 0; nto < 8; ++nto)
                qkv[(size_t)(b * 2048 + row) * 3072 + h * 128 + nto * 16 + l15] =
                    f2u(o[nto][r] * inv);
        }
    }
}

// ---------------------------------------------------------------------------
// Workspace layout (peak 46.1 MiB, proven):
//   [0,         8388608)  WoT   [2048][2048]   live until final GEMM
//   [8388608,  33554432)  QKV   [4096][3072]   q-slice becomes O in-place
//   [33554432, 37748736)  vT    [8][128][2048] written AFTER WTqkv is dead
//   [33554432, 46137344)  WTqkv [3072][2048]   dead after QKV GEMM
// xbf (bf16 copy of x, 16.8 MB) lives in d_out (dead until final GEMM).
extern "C" void kernel_launch(void* const* d_in, const int* in_sizes, int n_in,
                              void* d_out, int out_size, void* d_ws, size_t ws_size,
                              hipStream_t stream) {
    const float* x  = (const float*)d_in[0];   // [2,2048,2048] fp32
    const float* Wq = (const float*)d_in[1];   // [2048,2048]
    const float* Wk = (const float*)d_in[2];   // [2048,512]
    const float* Wv = (const float*)d_in[3];   // [2048,512]
    const float* Wo = (const float*)d_in[4];   // [2048,2048]
    const float* qg = (const float*)d_in[5];   // [128]
    const float* kg = (const float*)d_in[6];   // [128]

    char* ws = (char*)d_ws;
    u16* WoT   = (u16*)(ws);
    u16* QKV   = (u16*)(ws + 8388608);
    u16* vT    = (u16*)(ws + 33554432);
    u16* WTqkv = (u16*)(ws + 33554432);
    u16* xbf   = (u16*)d_out;                  // 16.8 MB of 33.5 MB; dead at GEMM2

    // 0. x->bf16 + all weight transposes, one launch
    prep<<<dim3(6656), 256, 0, stream>>>(x, Wq, Wk, Wv, Wo, xbf, WTqkv, WoT);

    // 1. QKV projection with fused per-head RMSNorm on q/k tiles
    gemm_lds<<<dim3(24, 32), 256, 0, stream>>>(xbf, 2048, WTqkv, QKV, 3072,
                                               nullptr, 0, 4096, 3072, 2048,
                                               qg, kg, 1);

    // 2. V transpose (WTqkv now dead; vT overlays it)
    vtrans<<<dim3(32, 4, 2), 256, 0, stream>>>(QKV, vT);

    // 3. causal GQA flash attention (paired q-tiles, register-resident P,
    //    8 waves: parallel tile wave-groups, 2x occupancy)
    attn<<<dim3(16, 16, 2), 512, 0, stream>>>(QKV, vT);

    // 4. output projection + residual (C = d_out fp32)
    gemm_lds<<<dim3(16, 32), 256, 0, stream>>>(QKV, 3072, WoT, d_out, 2048,
                                               x, 1, 4096, 2048, 2048,
                                               nullptr, nullptr, 0);
}